// Round 10
// baseline (313.920 us; speedup 1.0000x reference)
//
#include <hip/hip_runtime.h>
#include <stdint.h>

typedef float f32x4 __attribute__((ext_vector_type(4)));
typedef __bf16 bf16x8 __attribute__((ext_vector_type(8)));

#define DEV __device__ __forceinline__

DEV unsigned short f2bf(float f) {
  unsigned u = __float_as_uint(f);
  u += 0x7FFFu + ((u >> 16) & 1u);   // round-to-nearest-even
  return (unsigned short)(u >> 16);
}

DEV float exp2_(float x) {
#if __has_builtin(__builtin_amdgcn_exp2f)
  return __builtin_amdgcn_exp2f(x);   // raw v_exp_f32; args in [-60,0] => normal range
#else
  return exp2f(x);
#endif
}

// scal: [0..3]=wmax(q,kv,sr,proj), [4]=qmax, [5]=kmax, [6]=vmax, [7]=pmin, [8]=pmax
__global__ void k_init(float* scal) {
  int t = threadIdx.x;
  if (t < 16) scal[t] = (t == 7) ? __uint_as_float(0x7f800000u) : 0.f;
}

__global__ __launch_bounds__(256) void k_absmax4(const float* w0, const float* w1,
                                                 const float* w2, const float* w3, float* scal) {
  const float* srcs[4] = {w0, w1, w2, w3};
  const int ns[4] = {65536, 131072, 1048576, 65536};
  int t = blockIdx.y;
  const float* src = srcs[t];
  int n = ns[t];
  float m = 0.f;
  for (int i = blockIdx.x * 256 + threadIdx.x; i < n; i += gridDim.x * 256)
    m = fmaxf(m, fabsf(src[i]));
  #pragma unroll
  for (int d = 1; d < 64; d <<= 1) m = fmaxf(m, __shfl_xor(m, d, 64));
  __shared__ float red[4];
  if ((threadIdx.x & 63) == 0) red[threadIdx.x >> 6] = m;
  __syncthreads();
  if (threadIdx.x == 0) {
    m = fmaxf(fmaxf(red[0], red[1]), fmaxf(red[2], red[3]));
    atomicMax((unsigned*)(scal + t), __float_as_uint(m));
  }
}

__global__ __launch_bounds__(256) void k_quantw(const float* w, unsigned short* o, int n,
                                                const float* scal, int slot) {
  int i = blockIdx.x * 256 + threadIdx.x;
  if (i >= n) return;
  float delta = scal[slot] / 127.f + 1e-8f;
  float q = fminf(fmaxf(rintf(w[i] / delta), -128.f), 127.f) * delta;
  o[i] = f2bf(q);
}

// sr_w (O=256,I=256,4,4) -> W'[o][khkw*256 + i]  (k-order matches fused im2col)
__global__ __launch_bounds__(256) void k_quantsrw(const float* w, unsigned short* o, const float* scal) {
  int tid = blockIdx.x * 256 + threadIdx.x;
  int oo = tid >> 12;
  int rem = tid & 4095;
  int khkw = rem >> 8;
  int i = rem & 255;
  float delta = scal[2] / 127.f + 1e-8f;
  float x = w[oo * 4096 + i * 16 + khkw];
  float q = fminf(fmaxf(rintf(x / delta), -128.f), 127.f) * delta;
  o[tid] = f2bf(q);
}

// ---- 64x64-tile GEMM, K=256, BK=128 (kv: M=2048,N=512) ----
template<bool CVT>
__global__ __launch_bounds__(256) void k_gemm_bk(const void* __restrict__ Ap,
                                                 const unsigned short* __restrict__ W,
                                                 const float* __restrict__ bias,
                                                 float* __restrict__ C,
                                                 int M, int N, float* max_ptr, int split) {
  __shared__ unsigned short As[64 * 136];
  __shared__ unsigned short Bs[64 * 136];
  const int m0 = blockIdx.y * 64, n0 = blockIdx.x * 64;
  const int tid = threadIdx.x;
  const int wid = tid >> 6, lane = tid & 63;
  const int quad = lane >> 4, lr = lane & 15;
  const int wm = wid >> 1, wn = wid & 1;
  f32x4 acc[2][2] = {};
  for (int kb = 0; kb < 256; kb += 128) {
    __syncthreads();
    #pragma unroll
    for (int i = 0; i < 4; i++) {
      int c = i * 256 + tid;              // 1024 chunks of 8 elems
      int row = c >> 4, cu = (c & 15) * 8;
      if (CVT) {
        const float* Af = (const float*)Ap;
        const float* src = Af + (size_t)(m0 + row) * 256 + kb + cu;
        float4 v0 = *(const float4*)src;
        float4 v1 = *(const float4*)(src + 4);
        ushort4 r0, r1;
        r0.x = f2bf(v0.x); r0.y = f2bf(v0.y); r0.z = f2bf(v0.z); r0.w = f2bf(v0.w);
        r1.x = f2bf(v1.x); r1.y = f2bf(v1.y); r1.z = f2bf(v1.z); r1.w = f2bf(v1.w);
        *(ushort4*)&As[row * 136 + cu] = r0;
        *(ushort4*)&As[row * 136 + cu + 4] = r1;
      } else {
        const unsigned short* Ab = (const unsigned short*)Ap;
        *(uint4*)&As[row * 136 + cu] = *(const uint4*)(Ab + (size_t)(m0 + row) * 256 + kb + cu);
      }
      *(uint4*)&Bs[row * 136 + cu] = *(const uint4*)(W + (size_t)(n0 + row) * 256 + kb + cu);
    }
    __syncthreads();
    #pragma unroll
    for (int kc = 0; kc < 4; kc++) {
      bf16x8 af0 = *(const bf16x8*)&As[(wm * 32 + lr) * 136 + kc * 32 + quad * 8];
      bf16x8 af1 = *(const bf16x8*)&As[(wm * 32 + 16 + lr) * 136 + kc * 32 + quad * 8];
      bf16x8 bf0 = *(const bf16x8*)&Bs[(wn * 32 + lr) * 136 + kc * 32 + quad * 8];
      bf16x8 bf1 = *(const bf16x8*)&Bs[(wn * 32 + 16 + lr) * 136 + kc * 32 + quad * 8];
      acc[0][0] = __builtin_amdgcn_mfma_f32_16x16x32_bf16(af0, bf0, acc[0][0], 0, 0, 0);
      acc[0][1] = __builtin_amdgcn_mfma_f32_16x16x32_bf16(af0, bf1, acc[0][1], 0, 0, 0);
      acc[1][0] = __builtin_amdgcn_mfma_f32_16x16x32_bf16(af1, bf0, acc[1][0], 0, 0, 0);
      acc[1][1] = __builtin_amdgcn_mfma_f32_16x16x32_bf16(af1, bf1, acc[1][1], 0, 0, 0);
    }
  }
  float amax = 0.f;
  #pragma unroll
  for (int mi = 0; mi < 2; mi++)
    #pragma unroll
    for (int ni = 0; ni < 2; ni++) {
      int col = n0 + wn * 32 + ni * 16 + lr;
      float bv = bias[col];
      #pragma unroll
      for (int r = 0; r < 4; r++) {
        int row = m0 + wm * 32 + mi * 16 + quad * 4 + r;
        float v = acc[mi][ni][r] + bv;
        C[(size_t)row * N + col] = v;
        amax = fmaxf(amax, fabsf(v));
      }
    }
  if (max_ptr) {
    #pragma unroll
    for (int d = 1; d < 64; d <<= 1) amax = fmaxf(amax, __shfl_xor(amax, d, 64));
    if (lane == 0) {
      int slot = (split > 0 && n0 >= split) ? 1 : 0;
      atomicMax((unsigned*)(max_ptr + slot), __float_as_uint(amax));
    }
  }
}

// ---- 128x128-tile GEMM, K=256, BK=64; 4 waves, 2x2 layout, 64x64 patch/wave ----
template<bool CVT>
__global__ __launch_bounds__(256) void k_gemm128(const void* __restrict__ Ap,
                                                 const unsigned short* __restrict__ W,
                                                 const float* __restrict__ bias,
                                                 float* __restrict__ C,
                                                 int M, int N, float* max_ptr) {
  __shared__ unsigned short As[128 * 72];  // +8 pad: 2-way-max banking
  __shared__ unsigned short Bs[128 * 72];
  const int m0 = blockIdx.y * 128, n0 = blockIdx.x * 128;
  const int tid = threadIdx.x;
  const int wid = tid >> 6, lane = tid & 63;   // 4 waves
  const int quad = lane >> 4, lr = lane & 15;
  const int wm = wid >> 1, wn = wid & 1;       // 2x2 wave grid, 64x64 patch each
  f32x4 acc[4][4] = {};
  for (int kb = 0; kb < 256; kb += 64) {
    __syncthreads();
    #pragma unroll
    for (int i = 0; i < 4; i++) {
      int c = i * 256 + tid;             // 1024 chunks of 8 shorts
      int row = c >> 3, cu = (c & 7) * 8;
      if (CVT) {
        const float* Af = (const float*)Ap;
        const float* src = Af + (size_t)(m0 + row) * 256 + kb + cu;
        float4 v0 = *(const float4*)src;
        float4 v1 = *(const float4*)(src + 4);
        ushort4 r0, r1;
        r0.x = f2bf(v0.x); r0.y = f2bf(v0.y); r0.z = f2bf(v0.z); r0.w = f2bf(v0.w);
        r1.x = f2bf(v1.x); r1.y = f2bf(v1.y); r1.z = f2bf(v1.z); r1.w = f2bf(v1.w);
        *(ushort4*)&As[row * 72 + cu] = r0;
        *(ushort4*)&As[row * 72 + cu + 4] = r1;
      } else {
        const unsigned short* Ab = (const unsigned short*)Ap;
        *(uint4*)&As[row * 72 + cu] = *(const uint4*)(Ab + (size_t)(m0 + row) * 256 + kb + cu);
      }
      *(uint4*)&Bs[row * 72 + cu] = *(const uint4*)(W + (size_t)(n0 + row) * 256 + kb + cu);
    }
    __syncthreads();
    #pragma unroll
    for (int kc = 0; kc < 2; kc++) {
      bf16x8 af[4], bf[4];
      #pragma unroll
      for (int mi = 0; mi < 4; mi++)
        af[mi] = *(const bf16x8*)&As[(wm * 64 + mi * 16 + lr) * 72 + kc * 32 + quad * 8];
      #pragma unroll
      for (int ni = 0; ni < 4; ni++)
        bf[ni] = *(const bf16x8*)&Bs[(wn * 64 + ni * 16 + lr) * 72 + kc * 32 + quad * 8];
      #pragma unroll
      for (int mi = 0; mi < 4; mi++)
        #pragma unroll
        for (int ni = 0; ni < 4; ni++)
          acc[mi][ni] = __builtin_amdgcn_mfma_f32_16x16x32_bf16(af[mi], bf[ni], acc[mi][ni], 0, 0, 0);
    }
  }
  float amax = 0.f;
  #pragma unroll
  for (int mi = 0; mi < 4; mi++)
    #pragma unroll
    for (int ni = 0; ni < 4; ni++) {
      int col = n0 + wn * 64 + ni * 16 + lr;
      float bv = bias[col];
      #pragma unroll
      for (int r = 0; r < 4; r++) {
        int row = m0 + wm * 64 + mi * 16 + quad * 4 + r;
        float v = acc[mi][ni][r] + bv;
        C[(size_t)row * N + col] = v;
        amax = fmaxf(amax, fabsf(v));
      }
    }
  if (max_ptr) {
    #pragma unroll
    for (int d = 1; d < 64; d <<= 1) amax = fmaxf(amax, __shfl_xor(amax, d, 64));
    if (lane == 0) atomicMax((unsigned*)max_ptr, __float_as_uint(amax));
  }
}

// ---- conv GEMM: 2048x256xK4096, split-K=4, im2col+f32->bf16 fused into staging ----
__global__ __launch_bounds__(256) void k_conv_sk(const float* __restrict__ x,
                                                 const unsigned short* __restrict__ W,
                                                 float* __restrict__ C) {
  __shared__ unsigned short As[64 * 136];
  __shared__ unsigned short Bs[64 * 136];
  const int m0 = blockIdx.y * 64, n0 = blockIdx.x * 64;
  const int kOff = blockIdx.z * 1024;
  C += (size_t)blockIdx.z * 2048 * 256;
  const int tid = threadIdx.x;
  const int wid = tid >> 6, lane = tid & 63;
  const int quad = lane >> 4, lr = lane & 15;
  const int wm = wid >> 1, wn = wid & 1;
  f32x4 acc[2][2] = {};
  for (int kb = 0; kb < 1024; kb += 128) {
    __syncthreads();
    #pragma unroll
    for (int i = 0; i < 4; i++) {
      int c = i * 256 + tid;
      int row = c >> 4, cu = (c & 15) * 8;
      int kk = kOff + kb + cu;
      int m = m0 + row;
      int b = m >> 8, p = m & 255, ph = p >> 4, pw = p & 15;
      int q = kk >> 8, ii = kk & 255;
      int n = (ph * 4 + (q >> 2)) * 64 + pw * 4 + (q & 3);
      const float* src = x + ((size_t)(b * 4096 + n) * 256 + ii);
      float4 v0 = *(const float4*)src;
      float4 v1 = *(const float4*)(src + 4);
      ushort4 r0, r1;
      r0.x = f2bf(v0.x); r0.y = f2bf(v0.y); r0.z = f2bf(v0.z); r0.w = f2bf(v0.w);
      r1.x = f2bf(v1.x); r1.y = f2bf(v1.y); r1.z = f2bf(v1.z); r1.w = f2bf(v1.w);
      *(ushort4*)&As[row * 136 + cu] = r0;
      *(ushort4*)&As[row * 136 + cu + 4] = r1;
      *(uint4*)&Bs[row * 136 + cu] = *(const uint4*)(W + (size_t)(n0 + row) * 4096 + kk);
    }
    __syncthreads();
    #pragma unroll
    for (int kc = 0; kc < 4; kc++) {
      bf16x8 af0 = *(const bf16x8*)&As[(wm * 32 + lr) * 136 + kc * 32 + quad * 8];
      bf16x8 af1 = *(const bf16x8*)&As[(wm * 32 + 16 + lr) * 136 + kc * 32 + quad * 8];
      bf16x8 bf0 = *(const bf16x8*)&Bs[(wn * 32 + lr) * 136 + kc * 32 + quad * 8];
      bf16x8 bf1 = *(const bf16x8*)&Bs[(wn * 32 + 16 + lr) * 136 + kc * 32 + quad * 8];
      acc[0][0] = __builtin_amdgcn_mfma_f32_16x16x32_bf16(af0, bf0, acc[0][0], 0, 0, 0);
      acc[0][1] = __builtin_amdgcn_mfma_f32_16x16x32_bf16(af0, bf1, acc[0][1], 0, 0, 0);
      acc[1][0] = __builtin_amdgcn_mfma_f32_16x16x32_bf16(af1, bf0, acc[1][0], 0, 0, 0);
      acc[1][1] = __builtin_amdgcn_mfma_f32_16x16x32_bf16(af1, bf1, acc[1][1], 0, 0, 0);
    }
  }
  #pragma unroll
  for (int mi = 0; mi < 2; mi++)
    #pragma unroll
    for (int ni = 0; ni < 2; ni++) {
      int col = n0 + wn * 32 + ni * 16 + lr;
      #pragma unroll
      for (int r = 0; r < 4; r++) {
        int row = m0 + wm * 32 + mi * 16 + quad * 4 + r;
        C[(size_t)row * 256 + col] = acc[mi][ni][r];
      }
    }
}

// LayerNorm over C=256; sums 4 split-K conv partials + sr_b first
__global__ __launch_bounds__(256) void k_ln(const float* __restrict__ convp, const float* srb,
                                            const float* g, const float* bb,
                                            unsigned short* __restrict__ xn) {
  int row = blockIdx.x, c = threadIdx.x;
  float v = srb[c];
  #pragma unroll
  for (int s = 0; s < 4; s++) v += convp[s * 524288 + row * 256 + c];
  __shared__ float red[4];
  float s = v;
  #pragma unroll
  for (int d = 1; d < 64; d <<= 1) s += __shfl_xor(s, d, 64);
  if ((c & 63) == 0) red[c >> 6] = s;
  __syncthreads();
  float mu = (red[0] + red[1] + red[2] + red[3]) * (1.f / 256.f);
  __syncthreads();
  float dv = v - mu;
  float s2 = dv * dv;
  #pragma unroll
  for (int d = 1; d < 64; d <<= 1) s2 += __shfl_xor(s2, d, 64);
  if ((c & 63) == 0) red[c >> 6] = s2;
  __syncthreads();
  float var = (red[0] + red[1] + red[2] + red[3]) * (1.f / 256.f);
  float rs = 1.f / sqrtf(var + 1e-5f);
  xn[row * 256 + c] = f2bf(dv * rs * g[c] + bb[c]);
}

// q (32768x256 f32) -> quantize -> qq[b,h,n,j] bf16; 4 elems/thread (j stays in one head)
__global__ __launch_bounds__(256) void k_quant_q(const float* __restrict__ q,
                                                 unsigned short* __restrict__ qq,
                                                 const float* scal) {
  int tid = blockIdx.x * 256 + threadIdx.x;
  int i4 = tid * 4;
  float delta = scal[4] / 127.f + 1e-8f;
  float4 v = *(const float4*)(q + i4);
  int c = i4 & 255, bn = i4 >> 8;
  int b = bn >> 12, n = bn & 4095;
  int h = c >> 5, j = c & 31;   // j multiple of 4, j+3 <= 31
  ushort4 r;
  r.x = f2bf(fminf(fmaxf(rintf(v.x / delta), -128.f), 127.f) * delta);
  r.y = f2bf(fminf(fmaxf(rintf(v.y / delta), -128.f), 127.f) * delta);
  r.z = f2bf(fminf(fmaxf(rintf(v.z / delta), -128.f), 127.f) * delta);
  r.w = f2bf(fminf(fmaxf(rintf(v.w / delta), -128.f), 127.f) * delta);
  *(ushort4*)(qq + (((size_t)(b * 8 + h) * 4096 + n) * 32) + j) = r;
}

// kv (2048x512 f32) -> kq[b,h,n2,j] and vqt[b,h,j,n2] bf16
__global__ __launch_bounds__(256) void k_quant_kv(const float* __restrict__ kv,
                                                  unsigned short* __restrict__ kq,
                                                  unsigned short* __restrict__ vqt,
                                                  const float* scal) {
  int tid = blockIdx.x * 256 + threadIdx.x;
  int d = tid & 511, row = tid >> 9;
  int b = row >> 8, n2 = row & 255;
  int t = d >> 8, hj = d & 255;
  int h = hj >> 5, j = hj & 31;
  float delta = scal[5 + t] / 127.f + 1e-8f;
  float qv = fminf(fmaxf(rintf(kv[tid] / delta), -128.f), 127.f) * delta;
  unsigned short r = f2bf(qv);
  if (t == 0) kq[((b * 8 + h) * 256 + n2) * 32 + j] = r;
  else        vqt[((b * 8 + h) * 32 + j) * 256 + n2] = r;
}

// attention pass 1 (exp2 domain): per-row (m2, inv_l) -> rowstats;
// per-BLOCK (wmin, wmax) -> pstat[4096] (no contended atomics).
__global__ __launch_bounds__(256) void k_attn1(const unsigned short* __restrict__ qq,
                                               const unsigned short* __restrict__ kq,
                                               float2* __restrict__ rowstats,
                                               float2* __restrict__ pstat) {
  __shared__ unsigned short Ks[256 * 40];
  __shared__ float red[8];
  const int bh = blockIdx.y;
  const int row0 = blockIdx.x * 64;
  const int tid = threadIdx.x, wid = tid >> 6, lane = tid & 63, quad = lane >> 4, lr = lane & 15;
  const float c2 = 0.17677669529663687f * 1.4426950408889634f;  // 32^-0.5 * log2(e)
  const unsigned short* kbase = kq + (size_t)bh * 256 * 32;
  #pragma unroll
  for (int k = 0; k < 4; k++) {
    int cc = tid + k * 256;
    int rr = cc >> 2, c8 = (cc & 3) * 8;
    *(uint4*)&Ks[rr * 40 + c8] = *(const uint4*)(kbase + rr * 32 + c8);
  }
  __syncthreads();
  bf16x8 af = *(const bf16x8*)(qq + ((size_t)bh * 4096 + row0 + wid * 16 + lr) * 32 + quad * 8);
  f32x4 acc[16] = {};
  #pragma unroll
  for (int t = 0; t < 16; t++) {
    bf16x8 bfr = *(const bf16x8*)&Ks[(t * 16 + lr) * 40 + quad * 8];
    acc[t] = __builtin_amdgcn_mfma_f32_16x16x32_bf16(af, bfr, acc[t], 0, 0, 0);
  }
  float mx4[4], mn4[4];
  #pragma unroll
  for (int r = 0; r < 4; r++) {
    float mx = -1e30f, mn = 1e30f;
    #pragma unroll
    for (int t = 0; t < 16; t++) {
      float s = acc[t][r] * c2;
      mx = fmaxf(mx, s); mn = fminf(mn, s);
    }
    mx4[r] = mx; mn4[r] = mn;
  }
  #pragma unroll
  for (int d = 1; d < 16; d <<= 1) {
    #pragma unroll
    for (int r = 0; r < 4; r++) {
      mx4[r] = fmaxf(mx4[r], __shfl_xor(mx4[r], d, 64));
      mn4[r] = fminf(mn4[r], __shfl_xor(mn4[r], d, 64));
    }
  }
  float l4[4];
  #pragma unroll
  for (int r = 0; r < 4; r++) {
    float l = 0.f;
    #pragma unroll
    for (int t = 0; t < 16; t++) l += exp2_(acc[t][r] * c2 - mx4[r]);
    l4[r] = l;
  }
  #pragma unroll
  for (int d = 1; d < 16; d <<= 1) {
    #pragma unroll
    for (int r = 0; r < 4; r++) l4[r] += __shfl_xor(l4[r], d, 64);
  }
  float wmin = 1e30f, wmax = 0.f;
  #pragma unroll
  for (int r = 0; r < 4; r++) {
    float inv_l = 1.f / l4[r];
    int row = row0 + wid * 16 + quad * 4 + r;
    if (lr == 0) rowstats[(size_t)bh * 4096 + row] = make_float2(mx4[r], inv_l);
    wmax = fmaxf(wmax, inv_l);
    wmin = fminf(wmin, exp2_(mn4[r] - mx4[r]) * inv_l);
  }
  #pragma unroll
  for (int d = 16; d < 64; d <<= 1) {
    wmax = fmaxf(wmax, __shfl_xor(wmax, d, 64));
    wmin = fminf(wmin, __shfl_xor(wmin, d, 64));
  }
  if (lane == 0) { red[wid] = wmin; red[4 + wid] = wmax; }
  __syncthreads();
  if (tid == 0) {
    float mn = fminf(fminf(red[0], red[1]), fminf(red[2], red[3]));
    float mx = fmaxf(fmaxf(red[4], red[5]), fmaxf(red[6], red[7]));
    pstat[blockIdx.y * 64 + blockIdx.x] = make_float2(mn, mx);
  }
}

// reduce pstat[4096] -> scal[7]=pmin, scal[8]=pmax  (single block)
__global__ __launch_bounds__(256) void k_pminmax(const float2* __restrict__ pstat, float* scal) {
  int t = threadIdx.x;
  float mn = 1e30f, mx = 0.f;
  #pragma unroll
  for (int i = 0; i < 16; i++) {
    float2 v = pstat[t + i * 256];
    mn = fminf(mn, v.x); mx = fmaxf(mx, v.y);
  }
  #pragma unroll
  for (int d = 1; d < 64; d <<= 1) {
    mn = fminf(mn, __shfl_xor(mn, d, 64));
    mx = fmaxf(mx, __shfl_xor(mx, d, 64));
  }
  __shared__ float red[8];
  if ((t & 63) == 0) { red[t >> 6] = mn; red[4 + (t >> 6)] = mx; }
  __syncthreads();
  if (t == 0) {
    scal[7] = fminf(fminf(red[0], red[1]), fminf(red[2], red[3]));
    scal[8] = fmaxf(fmaxf(red[4], red[5]), fmaxf(red[6], red[7]));
  }
}

// attention pass 2: reduction-free; p = exp2(s*c2 - m2)*inv_l, asym quant, PV.
// LDS: Ps unioned over dead Ks (QK->PV phase transition); conflict-free strides.
__global__ __launch_bounds__(256) void k_attn2(const unsigned short* __restrict__ qq,
                                               const unsigned short* __restrict__ kq,
                                               const unsigned short* __restrict__ vqt,
                                               const float* scal,
                                               const float2* __restrict__ rowstats,
                                               unsigned short* __restrict__ attn_out) {
  __shared__ unsigned short Vs[32 * 266];     // 17.0 KB; stride 266: j8-groups bank-distinct
  __shared__ union {
    unsigned short Ks[256 * 40];              // 20.0 KB (QK phase)
    unsigned short Ps[64 * 268];              // 33.5 KB (PV phase); stride 268: quad-distinct
  } U;                                        // total LDS ~50.2 KB -> 3 blocks/CU
  const int bh = blockIdx.y, b = bh >> 3, h = bh & 7;
  const int row0 = blockIdx.x * 64;
  const int tid = threadIdx.x, wid = tid >> 6, lane = tid & 63, quad = lane >> 4, lr = lane & 15;
  const float c2 = 0.17677669529663687f * 1.4426950408889634f;
  const unsigned short* kbase = kq + (size_t)bh * 256 * 32;
  #pragma unroll
  for (int k = 0; k < 4; k++) {
    int cc = tid + k * 256;
    int rr = cc >> 2, c8 = (cc & 3) * 8;
    *(uint4*)&U.Ks[rr * 40 + c8] = *(const uint4*)(kbase + rr * 32 + c8);
  }
  const unsigned short* vbase = vqt + (size_t)bh * 32 * 256;
  #pragma unroll
  for (int k = 0; k < 4; k++) {
    int cc = tid + k * 256;
    int rr = cc >> 5, c8 = (cc & 31) * 8;
    *(uint4*)&Vs[rr * 266 + c8] = *(const uint4*)(vbase + rr * 256 + c8);
  }
  __syncthreads();
  bf16x8 af = *(const bf16x8*)(qq + ((size_t)bh * 4096 + row0 + wid * 16 + lr) * 32 + quad * 8);
  f32x4 acc[16] = {};
  #pragma unroll
  for (int t = 0; t < 16; t++) {
    bf16x8 bfr = *(const bf16x8*)&U.Ks[(t * 16 + lr) * 40 + quad * 8];
    acc[t] = __builtin_amdgcn_mfma_f32_16x16x32_bf16(af, bfr, acc[t], 0, 0, 0);
  }
  float pmin = scal[7], pmax = scal[8];
  float delta = (pmax - pmin) / 255.f + 1e-8f;
  float inv_delta = 1.f / delta;
  float zp = rintf(-pmin / delta);
  float lo = -zp, hi = 255.f - zp;     // clamp-shift: exact (integer-valued fp)
  __syncthreads();                     // Ks reads complete before Ps overwrite
  const int rowb = row0 + wid * 16 + quad * 4;
  #pragma unroll
  for (int r = 0; r < 4; r++) {
    float2 st = rowstats[(size_t)bh * 4096 + rowb + r];
    float m2 = st.x, inv_l = st.y;
    int prow = wid * 16 + quad * 4 + r;
    #pragma unroll
    for (int t = 0; t < 16; t++) {
      float p = exp2_(acc[t][r] * c2 - m2) * inv_l;
      float tq = fminf(fmaxf(rintf(p * inv_delta), lo), hi);
      U.Ps[prow * 268 + t * 16 + lr] = f2bf(tq * delta);
    }
  }
  __syncthreads();
  f32x4 o0 = {}, o1 = {};
  #pragma unroll
  for (int ks = 0; ks < 8; ks++) {
    bf16x8 pa = *(const bf16x8*)&U.Ps[(wid * 16 + lr) * 268 + ks * 32 + quad * 8];
    bf16x8 b0 = *(const bf16x8*)&Vs[lr * 266 + ks * 32 + quad * 8];
    bf16x8 b1 = *(const bf16x8*)&Vs[(16 + lr) * 266 + ks * 32 + quad * 8];
    o0 = __builtin_amdgcn_mfma_f32_16x16x32_bf16(pa, b0, o0, 0, 0, 0);
    o1 = __builtin_amdgcn_mfma_f32_16x16x32_bf16(pa, b1, o1, 0, 0, 0);
  }
  #pragma unroll
  for (int r = 0; r < 4; r++) {
    int n = row0 + wid * 16 + quad * 4 + r;
    size_t base = ((size_t)(b * 4096) + n) * 256 + h * 32;
    attn_out[base + lr] = f2bf(o0[r]);
    attn_out[base + 16 + lr] = f2bf(o1[r]);
  }
}

extern "C" void kernel_launch(void* const* d_in, const int* in_sizes, int n_in,
                              void* d_out, int out_size, void* d_ws, size_t ws_size,
                              hipStream_t stream) {
  const float* x      = (const float*)d_in[0];
  const float* q_w    = (const float*)d_in[1];
  const float* q_b    = (const float*)d_in[2];
  const float* kv_w   = (const float*)d_in[3];
  const float* kv_b   = (const float*)d_in[4];
  const float* sr_w   = (const float*)d_in[5];
  const float* sr_b   = (const float*)d_in[6];
  const float* norm_g = (const float*)d_in[7];
  const float* norm_b = (const float*)d_in[8];
  const float* proj_w = (const float*)d_in[9];
  const float* proj_b = (const float*)d_in[10];
  float* out = (float*)d_out;

  char* ws = (char*)d_ws;
  float* scal = (float*)ws;
  unsigned short* q_wq    = (unsigned short*)(ws + 256);       // 128 KB
  unsigned short* kv_wq   = (unsigned short*)(ws + 131328);    // 256 KB
  unsigned short* proj_wq = (unsigned short*)(ws + 393472);    // 128 KB
  unsigned short* sr_wq   = (unsigned short*)(ws + 524544);    // 2 MB   -> 2621696
  unsigned short* xn      = (unsigned short*)(ws + 2621696);   // 1 MB   -> 3670272
  float*          kv_f    = (float*)(ws + 3670272);            // 4 MB   -> 7864576
  unsigned short* kq      = (unsigned short*)(ws + 7864576);   // 1 MB   -> 8913152
  unsigned short* vqt     = (unsigned short*)(ws + 8913152);   // 1 MB   -> 9961728
  float2*         rowstats= (float2*)(ws + 9961728);           // 2 MB   -> 12058880
  float*          convp   = (float*)(ws + 12058880);           // 8 MB (4 partials) -> 20447488
  // aliases (stream-ordered lifetimes):
  float*          q_f     = (float*)(ws + 12058880);           // over convp (dead after k_ln); 32 MB -> 45613312
  unsigned short* qq      = (unsigned short*)(ws + 45613312);  // 16 MB -> 62390528
  unsigned short* attn_o  = (unsigned short*)(ws + 12058880);  // over q_f (dead after k_quant_q); 16 MB -> 28836096
  float2*         pstat   = (float2*)(ws + 28836096);          // 32 KB, in dead upper q_f region

  k_init<<<1, 64, 0, stream>>>(scal);
  k_absmax4<<<dim3(64, 4), 256, 0, stream>>>(q_w, kv_w, sr_w, proj_w, scal);
  k_quantw<<<256, 256, 0, stream>>>(q_w, q_wq, 65536, scal, 0);
  k_quantw<<<512, 256, 0, stream>>>(kv_w, kv_wq, 131072, scal, 1);
  k_quantsrw<<<4096, 256, 0, stream>>>(sr_w, sr_wq, scal);
  k_quantw<<<256, 256, 0, stream>>>(proj_w, proj_wq, 65536, scal, 3);
  // conv GEMM (im2col+cast fused, split-K=4): 2048x256x4096
  k_conv_sk<<<dim3(4, 32, 4), 256, 0, stream>>>(x, sr_wq, convp);
  k_ln<<<2048, 256, 0, stream>>>(convp, sr_b, norm_g, norm_b, xn);
  // kv GEMM: 2048x512x256
  k_gemm_bk<false><<<dim3(8, 32), 256, 0, stream>>>(xn, kv_wq, kv_b, kv_f, 2048, 512, scal + 5, 256);
  // q GEMM: 32768x256x256, 128-tile (reads x f32, converts in staging)
  k_gemm128<true><<<dim3(2, 256), 256, 0, stream>>>(x, q_wq, q_b, q_f, 32768, 256, scal + 4);
  k_quant_q<<<8192, 256, 0, stream>>>(q_f, qq, scal);
  k_quant_kv<<<4096, 256, 0, stream>>>(kv_f, kq, vqt, scal);
  k_attn1<<<dim3(64, 64), 256, 0, stream>>>(qq, kq, rowstats, pstat);
  k_pminmax<<<1, 256, 0, stream>>>(pstat, scal);
  k_attn2<<<dim3(64, 64), 256, 0, stream>>>(qq, kq, vqt, scal, rowstats, attn_o);
  // proj GEMM: 32768x256x256, 128-tile
  k_gemm128<false><<<dim3(2, 256), 256, 0, stream>>>(attn_o, proj_wq, proj_b, out, 32768, 256, nullptr);
}

// Round 11
// 312.331 us; speedup vs baseline: 1.0051x; 1.0051x over previous
//
#include <hip/hip_runtime.h>
#include <stdint.h>

typedef float f32x4 __attribute__((ext_vector_type(4)));
typedef __bf16 bf16x8 __attribute__((ext_vector_type(8)));

#define DEV __device__ __forceinline__

DEV unsigned short f2bf(float f) {
  unsigned u = __float_as_uint(f);
  u += 0x7FFFu + ((u >> 16) & 1u);   // round-to-nearest-even
  return (unsigned short)(u >> 16);
}

DEV float exp2_(float x) {
#if __has_builtin(__builtin_amdgcn_exp2f)
  return __builtin_amdgcn_exp2f(x);   // raw v_exp_f32; args in [-60,0] => normal range
#else
  return exp2f(x);
#endif
}

// scal: [0..3]=wmax(q,kv,sr,proj), [4]=qmax, [5]=kmax, [6]=vmax, [7]=pmin, [8]=pmax
__global__ void k_init(float* scal) {
  int t = threadIdx.x;
  if (t < 16) scal[t] = (t == 7) ? __uint_as_float(0x7f800000u) : 0.f;
}

__global__ __launch_bounds__(256) void k_absmax4(const float* w0, const float* w1,
                                                 const float* w2, const float* w3, float* scal) {
  const float* srcs[4] = {w0, w1, w2, w3};
  const int ns[4] = {65536, 131072, 1048576, 65536};
  int t = blockIdx.y;
  const float* src = srcs[t];
  int n = ns[t];
  float m = 0.f;
  for (int i = blockIdx.x * 256 + threadIdx.x; i < n; i += gridDim.x * 256)
    m = fmaxf(m, fabsf(src[i]));
  #pragma unroll
  for (int d = 1; d < 64; d <<= 1) m = fmaxf(m, __shfl_xor(m, d, 64));
  __shared__ float red[4];
  if ((threadIdx.x & 63) == 0) red[threadIdx.x >> 6] = m;
  __syncthreads();
  if (threadIdx.x == 0) {
    m = fmaxf(fmaxf(red[0], red[1]), fmaxf(red[2], red[3]));
    atomicMax((unsigned*)(scal + t), __float_as_uint(m));
  }
}

__global__ __launch_bounds__(256) void k_quantw(const float* w, unsigned short* o, int n,
                                                const float* scal, int slot) {
  int i = blockIdx.x * 256 + threadIdx.x;
  if (i >= n) return;
  float delta = scal[slot] / 127.f + 1e-8f;
  float q = fminf(fmaxf(rintf(w[i] / delta), -128.f), 127.f) * delta;
  o[i] = f2bf(q);
}

// sr_w (O=256,I=256,4,4) -> W'[o][khkw*256 + i]  (k-order matches fused im2col)
__global__ __launch_bounds__(256) void k_quantsrw(const float* w, unsigned short* o, const float* scal) {
  int tid = blockIdx.x * 256 + threadIdx.x;
  int oo = tid >> 12;
  int rem = tid & 4095;
  int khkw = rem >> 8;
  int i = rem & 255;
  float delta = scal[2] / 127.f + 1e-8f;
  float x = w[oo * 4096 + i * 16 + khkw];
  float q = fminf(fmaxf(rintf(x / delta), -128.f), 127.f) * delta;
  o[tid] = f2bf(q);
}

// ---- 64x64-tile GEMM, K=256, BK=128 (kv: M=2048,N=512) ----
template<bool CVT>
__global__ __launch_bounds__(256) void k_gemm_bk(const void* __restrict__ Ap,
                                                 const unsigned short* __restrict__ W,
                                                 const float* __restrict__ bias,
                                                 float* __restrict__ C,
                                                 int M, int N, float* max_ptr, int split) {
  __shared__ unsigned short As[64 * 136];
  __shared__ unsigned short Bs[64 * 136];
  const int m0 = blockIdx.y * 64, n0 = blockIdx.x * 64;
  const int tid = threadIdx.x;
  const int wid = tid >> 6, lane = tid & 63;
  const int quad = lane >> 4, lr = lane & 15;
  const int wm = wid >> 1, wn = wid & 1;
  f32x4 acc[2][2] = {};
  for (int kb = 0; kb < 256; kb += 128) {
    __syncthreads();
    #pragma unroll
    for (int i = 0; i < 4; i++) {
      int c = i * 256 + tid;              // 1024 chunks of 8 elems
      int row = c >> 4, cu = (c & 15) * 8;
      if (CVT) {
        const float* Af = (const float*)Ap;
        const float* src = Af + (size_t)(m0 + row) * 256 + kb + cu;
        float4 v0 = *(const float4*)src;
        float4 v1 = *(const float4*)(src + 4);
        ushort4 r0, r1;
        r0.x = f2bf(v0.x); r0.y = f2bf(v0.y); r0.z = f2bf(v0.z); r0.w = f2bf(v0.w);
        r1.x = f2bf(v1.x); r1.y = f2bf(v1.y); r1.z = f2bf(v1.z); r1.w = f2bf(v1.w);
        *(ushort4*)&As[row * 136 + cu] = r0;
        *(ushort4*)&As[row * 136 + cu + 4] = r1;
      } else {
        const unsigned short* Ab = (const unsigned short*)Ap;
        *(uint4*)&As[row * 136 + cu] = *(const uint4*)(Ab + (size_t)(m0 + row) * 256 + kb + cu);
      }
      *(uint4*)&Bs[row * 136 + cu] = *(const uint4*)(W + (size_t)(n0 + row) * 256 + kb + cu);
    }
    __syncthreads();
    #pragma unroll
    for (int kc = 0; kc < 4; kc++) {
      bf16x8 af0 = *(const bf16x8*)&As[(wm * 32 + lr) * 136 + kc * 32 + quad * 8];
      bf16x8 af1 = *(const bf16x8*)&As[(wm * 32 + 16 + lr) * 136 + kc * 32 + quad * 8];
      bf16x8 bf0 = *(const bf16x8*)&Bs[(wn * 32 + lr) * 136 + kc * 32 + quad * 8];
      bf16x8 bf1 = *(const bf16x8*)&Bs[(wn * 32 + 16 + lr) * 136 + kc * 32 + quad * 8];
      acc[0][0] = __builtin_amdgcn_mfma_f32_16x16x32_bf16(af0, bf0, acc[0][0], 0, 0, 0);
      acc[0][1] = __builtin_amdgcn_mfma_f32_16x16x32_bf16(af0, bf1, acc[0][1], 0, 0, 0);
      acc[1][0] = __builtin_amdgcn_mfma_f32_16x16x32_bf16(af1, bf0, acc[1][0], 0, 0, 0);
      acc[1][1] = __builtin_amdgcn_mfma_f32_16x16x32_bf16(af1, bf1, acc[1][1], 0, 0, 0);
    }
  }
  float amax = 0.f;
  #pragma unroll
  for (int mi = 0; mi < 2; mi++)
    #pragma unroll
    for (int ni = 0; ni < 2; ni++) {
      int col = n0 + wn * 32 + ni * 16 + lr;
      float bv = bias[col];
      #pragma unroll
      for (int r = 0; r < 4; r++) {
        int row = m0 + wm * 32 + mi * 16 + quad * 4 + r;
        float v = acc[mi][ni][r] + bv;
        C[(size_t)row * N + col] = v;
        amax = fmaxf(amax, fabsf(v));
      }
    }
  if (max_ptr) {
    #pragma unroll
    for (int d = 1; d < 64; d <<= 1) amax = fmaxf(amax, __shfl_xor(amax, d, 64));
    if (lane == 0) {
      int slot = (split > 0 && n0 >= split) ? 1 : 0;
      atomicMax((unsigned*)(max_ptr + slot), __float_as_uint(amax));
    }
  }
}

// ---- 128x128-tile GEMM, K=256, BK=64; 4 waves, 2x2 layout, 64x64 patch/wave ----
template<bool CVT>
__global__ __launch_bounds__(256) void k_gemm128(const void* __restrict__ Ap,
                                                 const unsigned short* __restrict__ W,
                                                 const float* __restrict__ bias,
                                                 float* __restrict__ C,
                                                 int M, int N, float* max_ptr) {
  __shared__ unsigned short As[128 * 72];  // +8 pad: 2-way-max banking
  __shared__ unsigned short Bs[128 * 72];
  const int m0 = blockIdx.y * 128, n0 = blockIdx.x * 128;
  const int tid = threadIdx.x;
  const int wid = tid >> 6, lane = tid & 63;   // 4 waves
  const int quad = lane >> 4, lr = lane & 15;
  const int wm = wid >> 1, wn = wid & 1;       // 2x2 wave grid, 64x64 patch each
  f32x4 acc[4][4] = {};
  for (int kb = 0; kb < 256; kb += 64) {
    __syncthreads();
    #pragma unroll
    for (int i = 0; i < 4; i++) {
      int c = i * 256 + tid;             // 1024 chunks of 8 shorts
      int row = c >> 3, cu = (c & 7) * 8;
      if (CVT) {
        const float* Af = (const float*)Ap;
        const float* src = Af + (size_t)(m0 + row) * 256 + kb + cu;
        float4 v0 = *(const float4*)src;
        float4 v1 = *(const float4*)(src + 4);
        ushort4 r0, r1;
        r0.x = f2bf(v0.x); r0.y = f2bf(v0.y); r0.z = f2bf(v0.z); r0.w = f2bf(v0.w);
        r1.x = f2bf(v1.x); r1.y = f2bf(v1.y); r1.z = f2bf(v1.z); r1.w = f2bf(v1.w);
        *(ushort4*)&As[row * 72 + cu] = r0;
        *(ushort4*)&As[row * 72 + cu + 4] = r1;
      } else {
        const unsigned short* Ab = (const unsigned short*)Ap;
        *(uint4*)&As[row * 72 + cu] = *(const uint4*)(Ab + (size_t)(m0 + row) * 256 + kb + cu);
      }
      *(uint4*)&Bs[row * 72 + cu] = *(const uint4*)(W + (size_t)(n0 + row) * 256 + kb + cu);
    }
    __syncthreads();
    #pragma unroll
    for (int kc = 0; kc < 2; kc++) {
      bf16x8 af[4], bf[4];
      #pragma unroll
      for (int mi = 0; mi < 4; mi++)
        af[mi] = *(const bf16x8*)&As[(wm * 64 + mi * 16 + lr) * 72 + kc * 32 + quad * 8];
      #pragma unroll
      for (int ni = 0; ni < 4; ni++)
        bf[ni] = *(const bf16x8*)&Bs[(wn * 64 + ni * 16 + lr) * 72 + kc * 32 + quad * 8];
      #pragma unroll
      for (int mi = 0; mi < 4; mi++)
        #pragma unroll
        for (int ni = 0; ni < 4; ni++)
          acc[mi][ni] = __builtin_amdgcn_mfma_f32_16x16x32_bf16(af[mi], bf[ni], acc[mi][ni], 0, 0, 0);
    }
  }
  float amax = 0.f;
  #pragma unroll
  for (int mi = 0; mi < 4; mi++)
    #pragma unroll
    for (int ni = 0; ni < 4; ni++) {
      int col = n0 + wn * 64 + ni * 16 + lr;
      float bv = bias[col];
      #pragma unroll
      for (int r = 0; r < 4; r++) {
        int row = m0 + wm * 64 + mi * 16 + quad * 4 + r;
        float v = acc[mi][ni][r] + bv;
        C[(size_t)row * N + col] = v;
        amax = fmaxf(amax, fabsf(v));
      }
    }
  if (max_ptr) {
    #pragma unroll
    for (int d = 1; d < 64; d <<= 1) amax = fmaxf(amax, __shfl_xor(amax, d, 64));
    if (lane == 0) atomicMax((unsigned*)max_ptr, __float_as_uint(amax));
  }
}

// ---- conv GEMM: 2048x256xK4096, split-K=4, im2col+f32->bf16 fused into staging ----
__global__ __launch_bounds__(256) void k_conv_sk(const float* __restrict__ x,
                                                 const unsigned short* __restrict__ W,
                                                 float* __restrict__ C) {
  __shared__ unsigned short As[64 * 136];
  __shared__ unsigned short Bs[64 * 136];
  const int m0 = blockIdx.y * 64, n0 = blockIdx.x * 64;
  const int kOff = blockIdx.z * 1024;
  C += (size_t)blockIdx.z * 2048 * 256;
  const int tid = threadIdx.x;
  const int wid = tid >> 6, lane = tid & 63;
  const int quad = lane >> 4, lr = lane & 15;
  const int wm = wid >> 1, wn = wid & 1;
  f32x4 acc[2][2] = {};
  for (int kb = 0; kb < 1024; kb += 128) {
    __syncthreads();
    #pragma unroll
    for (int i = 0; i < 4; i++) {
      int c = i * 256 + tid;
      int row = c >> 4, cu = (c & 15) * 8;
      int kk = kOff + kb + cu;
      int m = m0 + row;
      int b = m >> 8, p = m & 255, ph = p >> 4, pw = p & 15;
      int q = kk >> 8, ii = kk & 255;
      int n = (ph * 4 + (q >> 2)) * 64 + pw * 4 + (q & 3);
      const float* src = x + ((size_t)(b * 4096 + n) * 256 + ii);
      float4 v0 = *(const float4*)src;
      float4 v1 = *(const float4*)(src + 4);
      ushort4 r0, r1;
      r0.x = f2bf(v0.x); r0.y = f2bf(v0.y); r0.z = f2bf(v0.z); r0.w = f2bf(v0.w);
      r1.x = f2bf(v1.x); r1.y = f2bf(v1.y); r1.z = f2bf(v1.z); r1.w = f2bf(v1.w);
      *(ushort4*)&As[row * 136 + cu] = r0;
      *(ushort4*)&As[row * 136 + cu + 4] = r1;
      *(uint4*)&Bs[row * 136 + cu] = *(const uint4*)(W + (size_t)(n0 + row) * 4096 + kk);
    }
    __syncthreads();
    #pragma unroll
    for (int kc = 0; kc < 4; kc++) {
      bf16x8 af0 = *(const bf16x8*)&As[(wm * 32 + lr) * 136 + kc * 32 + quad * 8];
      bf16x8 af1 = *(const bf16x8*)&As[(wm * 32 + 16 + lr) * 136 + kc * 32 + quad * 8];
      bf16x8 bf0 = *(const bf16x8*)&Bs[(wn * 32 + lr) * 136 + kc * 32 + quad * 8];
      bf16x8 bf1 = *(const bf16x8*)&Bs[(wn * 32 + 16 + lr) * 136 + kc * 32 + quad * 8];
      acc[0][0] = __builtin_amdgcn_mfma_f32_16x16x32_bf16(af0, bf0, acc[0][0], 0, 0, 0);
      acc[0][1] = __builtin_amdgcn_mfma_f32_16x16x32_bf16(af0, bf1, acc[0][1], 0, 0, 0);
      acc[1][0] = __builtin_amdgcn_mfma_f32_16x16x32_bf16(af1, bf0, acc[1][0], 0, 0, 0);
      acc[1][1] = __builtin_amdgcn_mfma_f32_16x16x32_bf16(af1, bf1, acc[1][1], 0, 0, 0);
    }
  }
  #pragma unroll
  for (int mi = 0; mi < 2; mi++)
    #pragma unroll
    for (int ni = 0; ni < 2; ni++) {
      int col = n0 + wn * 32 + ni * 16 + lr;
      #pragma unroll
      for (int r = 0; r < 4; r++) {
        int row = m0 + wm * 32 + mi * 16 + quad * 4 + r;
        C[(size_t)row * 256 + col] = acc[mi][ni][r];
      }
    }
}

// LayerNorm over C=256; sums 4 split-K conv partials + sr_b first
__global__ __launch_bounds__(256) void k_ln(const float* __restrict__ convp, const float* srb,
                                            const float* g, const float* bb,
                                            unsigned short* __restrict__ xn) {
  int row = blockIdx.x, c = threadIdx.x;
  float v = srb[c];
  #pragma unroll
  for (int s = 0; s < 4; s++) v += convp[s * 524288 + row * 256 + c];
  __shared__ float red[4];
  float s = v;
  #pragma unroll
  for (int d = 1; d < 64; d <<= 1) s += __shfl_xor(s, d, 64);
  if ((c & 63) == 0) red[c >> 6] = s;
  __syncthreads();
  float mu = (red[0] + red[1] + red[2] + red[3]) * (1.f / 256.f);
  __syncthreads();
  float dv = v - mu;
  float s2 = dv * dv;
  #pragma unroll
  for (int d = 1; d < 64; d <<= 1) s2 += __shfl_xor(s2, d, 64);
  if ((c & 63) == 0) red[c >> 6] = s2;
  __syncthreads();
  float var = (red[0] + red[1] + red[2] + red[3]) * (1.f / 256.f);
  float rs = 1.f / sqrtf(var + 1e-5f);
  xn[row * 256 + c] = f2bf(dv * rs * g[c] + bb[c]);
}

// q (32768x256 f32) -> quantize -> qq[b,h,n,j] bf16; 4 elems/thread (j stays in one head)
__global__ __launch_bounds__(256) void k_quant_q(const float* __restrict__ q,
                                                 unsigned short* __restrict__ qq,
                                                 const float* scal) {
  int tid = blockIdx.x * 256 + threadIdx.x;
  int i4 = tid * 4;
  float delta = scal[4] / 127.f + 1e-8f;
  float4 v = *(const float4*)(q + i4);
  int c = i4 & 255, bn = i4 >> 8;
  int b = bn >> 12, n = bn & 4095;
  int h = c >> 5, j = c & 31;   // j multiple of 4, j+3 <= 31
  ushort4 r;
  r.x = f2bf(fminf(fmaxf(rintf(v.x / delta), -128.f), 127.f) * delta);
  r.y = f2bf(fminf(fmaxf(rintf(v.y / delta), -128.f), 127.f) * delta);
  r.z = f2bf(fminf(fmaxf(rintf(v.z / delta), -128.f), 127.f) * delta);
  r.w = f2bf(fminf(fmaxf(rintf(v.w / delta), -128.f), 127.f) * delta);
  *(ushort4*)(qq + (((size_t)(b * 8 + h) * 4096 + n) * 32) + j) = r;
}

// kv (2048x512 f32) -> kq[b,h,n2,j] and vqt[b,h,j,n2] bf16
__global__ __launch_bounds__(256) void k_quant_kv(const float* __restrict__ kv,
                                                  unsigned short* __restrict__ kq,
                                                  unsigned short* __restrict__ vqt,
                                                  const float* scal) {
  int tid = blockIdx.x * 256 + threadIdx.x;
  int d = tid & 511, row = tid >> 9;
  int b = row >> 8, n2 = row & 255;
  int t = d >> 8, hj = d & 255;
  int h = hj >> 5, j = hj & 31;
  float delta = scal[5 + t] / 127.f + 1e-8f;
  float qv = fminf(fmaxf(rintf(kv[tid] / delta), -128.f), 127.f) * delta;
  unsigned short r = f2bf(qv);
  if (t == 0) kq[((b * 8 + h) * 256 + n2) * 32 + j] = r;
  else        vqt[((b * 8 + h) * 32 + j) * 256 + n2] = r;
}

// attention pass 1 (exp2 domain): per-row (m2, inv_l) -> rowstats;
// per-BLOCK (wmin, wmax) -> pstat[4096] (no contended atomics).
__global__ __launch_bounds__(256) void k_attn1(const unsigned short* __restrict__ qq,
                                               const unsigned short* __restrict__ kq,
                                               float2* __restrict__ rowstats,
                                               float2* __restrict__ pstat) {
  __shared__ unsigned short Ks[256 * 40];
  __shared__ float red[8];
  const int bh = blockIdx.y;
  const int row0 = blockIdx.x * 64;
  const int tid = threadIdx.x, wid = tid >> 6, lane = tid & 63, quad = lane >> 4, lr = lane & 15;
  const float c2 = 0.17677669529663687f * 1.4426950408889634f;  // 32^-0.5 * log2(e)
  const unsigned short* kbase = kq + (size_t)bh * 256 * 32;
  #pragma unroll
  for (int k = 0; k < 4; k++) {
    int cc = tid + k * 256;
    int rr = cc >> 2, c8 = (cc & 3) * 8;
    *(uint4*)&Ks[rr * 40 + c8] = *(const uint4*)(kbase + rr * 32 + c8);
  }
  __syncthreads();
  bf16x8 af = *(const bf16x8*)(qq + ((size_t)bh * 4096 + row0 + wid * 16 + lr) * 32 + quad * 8);
  f32x4 acc[16] = {};
  #pragma unroll
  for (int t = 0; t < 16; t++) {
    bf16x8 bfr = *(const bf16x8*)&Ks[(t * 16 + lr) * 40 + quad * 8];
    acc[t] = __builtin_amdgcn_mfma_f32_16x16x32_bf16(af, bfr, acc[t], 0, 0, 0);
  }
  float mx4[4], mn4[4];
  #pragma unroll
  for (int r = 0; r < 4; r++) {
    float mx = -1e30f, mn = 1e30f;
    #pragma unroll
    for (int t = 0; t < 16; t++) {
      float s = acc[t][r] * c2;
      mx = fmaxf(mx, s); mn = fminf(mn, s);
    }
    mx4[r] = mx; mn4[r] = mn;
  }
  #pragma unroll
  for (int d = 1; d < 16; d <<= 1) {
    #pragma unroll
    for (int r = 0; r < 4; r++) {
      mx4[r] = fmaxf(mx4[r], __shfl_xor(mx4[r], d, 64));
      mn4[r] = fminf(mn4[r], __shfl_xor(mn4[r], d, 64));
    }
  }
  float l4[4];
  #pragma unroll
  for (int r = 0; r < 4; r++) {
    float l = 0.f;
    #pragma unroll
    for (int t = 0; t < 16; t++) l += exp2_(acc[t][r] * c2 - mx4[r]);
    l4[r] = l;
  }
  #pragma unroll
  for (int d = 1; d < 16; d <<= 1) {
    #pragma unroll
    for (int r = 0; r < 4; r++) l4[r] += __shfl_xor(l4[r], d, 64);
  }
  float wmin = 1e30f, wmax = 0.f;
  #pragma unroll
  for (int r = 0; r < 4; r++) {
    float inv_l = 1.f / l4[r];
    int row = row0 + wid * 16 + quad * 4 + r;
    if (lr == 0) rowstats[(size_t)bh * 4096 + row] = make_float2(mx4[r], inv_l);
    wmax = fmaxf(wmax, inv_l);
    wmin = fminf(wmin, exp2_(mn4[r] - mx4[r]) * inv_l);
  }
  #pragma unroll
  for (int d = 16; d < 64; d <<= 1) {
    wmax = fmaxf(wmax, __shfl_xor(wmax, d, 64));
    wmin = fminf(wmin, __shfl_xor(wmin, d, 64));
  }
  if (lane == 0) { red[wid] = wmin; red[4 + wid] = wmax; }
  __syncthreads();
  if (tid == 0) {
    float mn = fminf(fminf(red[0], red[1]), fminf(red[2], red[3]));
    float mx = fmaxf(fmaxf(red[4], red[5]), fmaxf(red[6], red[7]));
    pstat[blockIdx.y * 64 + blockIdx.x] = make_float2(mn, mx);
  }
}

// reduce pstat[4096] -> scal[7]=pmin, scal[8]=pmax  (single block)
__global__ __launch_bounds__(256) void k_pminmax(const float2* __restrict__ pstat, float* scal) {
  int t = threadIdx.x;
  float mn = 1e30f, mx = 0.f;
  #pragma unroll
  for (int i = 0; i < 16; i++) {
    float2 v = pstat[t + i * 256];
    mn = fminf(mn, v.x); mx = fmaxf(mx, v.y);
  }
  #pragma unroll
  for (int d = 1; d < 64; d <<= 1) {
    mn = fminf(mn, __shfl_xor(mn, d, 64));
    mx = fmaxf(mx, __shfl_xor(mx, d, 64));
  }
  __shared__ float red[8];
  if ((t & 63) == 0) { red[t >> 6] = mn; red[4 + (t >> 6)] = mx; }
  __syncthreads();
  if (t == 0) {
    scal[7] = fminf(fminf(red[0], red[1]), fminf(red[2], red[3]));
    scal[8] = fmaxf(fmaxf(red[4], red[5]), fmaxf(red[6], red[7]));
  }
}

// attention pass 2: reduction-free; p = exp2(s*c2 - m2)*inv_l, asym quant, PV.
// LDS: Ps unioned over dead Ks; Vs stride 264 (uniform banks), Ps stride 268 (quad-distinct writes).
__global__ __launch_bounds__(256) void k_attn2(const unsigned short* __restrict__ qq,
                                               const unsigned short* __restrict__ kq,
                                               const unsigned short* __restrict__ vqt,
                                               const float* scal,
                                               const float2* __restrict__ rowstats,
                                               unsigned short* __restrict__ attn_out) {
  __shared__ unsigned short Vs[32 * 264];     // 16.5 KB; stride 264: read bases 4*((lr+quad)%8) uniform
  __shared__ union {
    unsigned short Ks[256 * 40];              // 20.0 KB (QK phase)
    unsigned short Ps[64 * 268];              // 33.5 KB (PV phase); stride 268: quad offsets {0,24,16,8}
  } U;                                        // total LDS ~50 KB -> 3 blocks/CU
  const int bh = blockIdx.y, b = bh >> 3, h = bh & 7;
  const int row0 = blockIdx.x * 64;
  const int tid = threadIdx.x, wid = tid >> 6, lane = tid & 63, quad = lane >> 4, lr = lane & 15;
  const float c2 = 0.17677669529663687f * 1.4426950408889634f;
  const unsigned short* kbase = kq + (size_t)bh * 256 * 32;
  #pragma unroll
  for (int k = 0; k < 4; k++) {
    int cc = tid + k * 256;
    int rr = cc >> 2, c8 = (cc & 3) * 8;
    *(uint4*)&U.Ks[rr * 40 + c8] = *(const uint4*)(kbase + rr * 32 + c8);
  }
  const unsigned short* vbase = vqt + (size_t)bh * 32 * 256;
  #pragma unroll
  for (int k = 0; k < 4; k++) {
    int cc = tid + k * 256;
    int rr = cc >> 5, c8 = (cc & 31) * 8;
    *(uint4*)&Vs[rr * 264 + c8] = *(const uint4*)(vbase + rr * 256 + c8);
  }
  __syncthreads();
  bf16x8 af = *(const bf16x8*)(qq + ((size_t)bh * 4096 + row0 + wid * 16 + lr) * 32 + quad * 8);
  f32x4 acc[16] = {};
  #pragma unroll
  for (int t = 0; t < 16; t++) {
    bf16x8 bfr = *(const bf16x8*)&U.Ks[(t * 16 + lr) * 40 + quad * 8];
    acc[t] = __builtin_amdgcn_mfma_f32_16x16x32_bf16(af, bfr, acc[t], 0, 0, 0);
  }
  float pmin = scal[7], pmax = scal[8];
  float delta = (pmax - pmin) / 255.f + 1e-8f;
  float inv_delta = 1.f / delta;
  float zp = rintf(-pmin / delta);
  float lo = -zp, hi = 255.f - zp;     // clamp-shift: exact (integer-valued fp)
  __syncthreads();                     // Ks reads complete before Ps overwrite
  const int rowb = row0 + wid * 16 + quad * 4;
  #pragma unroll
  for (int r = 0; r < 4; r++) {
    float2 st = rowstats[(size_t)bh * 4096 + rowb + r];
    float m2 = st.x, inv_l = st.y;
    int prow = wid * 16 + quad * 4 + r;
    #pragma unroll
    for (int t = 0; t < 16; t++) {
      float p = exp2_(acc[t][r] * c2 - m2) * inv_l;
      float tq = fminf(fmaxf(rintf(p * inv_delta), lo), hi);
      U.Ps[prow * 268 + t * 16 + lr] = f2bf(tq * delta);
    }
  }
  __syncthreads();
  f32x4 o0 = {}, o1 = {};
  #pragma unroll
  for (int ks = 0; ks < 8; ks++) {
    bf16x8 pa = *(const bf16x8*)&U.Ps[(wid * 16 + lr) * 268 + ks * 32 + quad * 8];
    bf16x8 b0 = *(const bf16x8*)&Vs[lr * 264 + ks * 32 + quad * 8];
    bf16x8 b1 = *(const bf16x8*)&Vs[(16 + lr) * 264 + ks * 32 + quad * 8];
    o0 = __builtin_amdgcn_mfma_f32_16x16x32_bf16(pa, b0, o0, 0, 0, 0);
    o1 = __builtin_amdgcn_mfma_f32_16x16x32_bf16(pa, b1, o1, 0, 0, 0);
  }
  #pragma unroll
  for (int r = 0; r < 4; r++) {
    int n = row0 + wid * 16 + quad * 4 + r;
    size_t base = ((size_t)(b * 4096) + n) * 256 + h * 32;
    attn_out[base + lr] = f2bf(o0[r]);
    attn_out[base + 16 + lr] = f2bf(o1[r]);
  }
}

extern "C" void kernel_launch(void* const* d_in, const int* in_sizes, int n_in,
                              void* d_out, int out_size, void* d_ws, size_t ws_size,
                              hipStream_t stream) {
  const float* x      = (const float*)d_in[0];
  const float* q_w    = (const float*)d_in[1];
  const float* q_b    = (const float*)d_in[2];
  const float* kv_w   = (const float*)d_in[3];
  const float* kv_b   = (const float*)d_in[4];
  const float* sr_w   = (const float*)d_in[5];
  const float* sr_b   = (const float*)d_in[6];
  const float* norm_g = (const float*)d_in[7];
  const float* norm_b = (const float*)d_in[8];
  const float* proj_w = (const float*)d_in[9];
  const float* proj_b = (const float*)d_in[10];
  float* out = (float*)d_out;

  char* ws = (char*)d_ws;
  float* scal = (float*)ws;
  unsigned short* q_wq    = (unsigned short*)(ws + 256);       // 128 KB
  unsigned short* kv_wq   = (unsigned short*)(ws + 131328);    // 256 KB
  unsigned short* proj_wq = (unsigned short*)(ws + 393472);    // 128 KB
  unsigned short* sr_wq   = (unsigned short*)(ws + 524544);    // 2 MB   -> 2621696
  unsigned short* xn      = (unsigned short*)(ws + 2621696);   // 1 MB   -> 3670272
  float*          kv_f    = (float*)(ws + 3670272);            // 4 MB   -> 7864576
  unsigned short* kq      = (unsigned short*)(ws + 7864576);   // 1 MB   -> 8913152
  unsigned short* vqt     = (unsigned short*)(ws + 8913152);   // 1 MB   -> 9961728
  float2*         rowstats= (float2*)(ws + 9961728);           // 2 MB   -> 12058880
  float*          convp   = (float*)(ws + 12058880);           // 8 MB (4 partials) -> 20447488
  // aliases (stream-ordered lifetimes):
  float*          q_f     = (float*)(ws + 12058880);           // over convp (dead after k_ln); 32 MB -> 45613312
  unsigned short* qq      = (unsigned short*)(ws + 45613312);  // 16 MB -> 62390528
  unsigned short* attn_o  = (unsigned short*)(ws + 12058880);  // over q_f (dead after k_quant_q); 16 MB -> 28836096
  float2*         pstat   = (float2*)(ws + 28836096);          // 32 KB, in dead upper q_f region

  k_init<<<1, 64, 0, stream>>>(scal);
  k_absmax4<<<dim3(64, 4), 256, 0, stream>>>(q_w, kv_w, sr_w, proj_w, scal);
  k_quantw<<<256, 256, 0, stream>>>(q_w, q_wq, 65536, scal, 0);
  k_quantw<<<512, 256, 0, stream>>>(kv_w, kv_wq, 131072, scal, 1);
  k_quantsrw<<<4096, 256, 0, stream>>>(sr_w, sr_wq, scal);
  k_quantw<<<256, 256, 0, stream>>>(proj_w, proj_wq, 65536, scal, 3);
  // conv GEMM (im2col+cast fused, split-K=4): 2048x256x4096
  k_conv_sk<<<dim3(4, 32, 4), 256, 0, stream>>>(x, sr_wq, convp);
  k_ln<<<2048, 256, 0, stream>>>(convp, sr_b, norm_g, norm_b, xn);
  // kv GEMM: 2048x512x256
  k_gemm_bk<false><<<dim3(8, 32), 256, 0, stream>>>(xn, kv_wq, kv_b, kv_f, 2048, 512, scal + 5, 256);
  // q GEMM: 32768x256x256, 128-tile (reads x f32, converts in staging)
  k_gemm128<true><<<dim3(2, 256), 256, 0, stream>>>(x, q_wq, q_b, q_f, 32768, 256, scal + 4);
  k_quant_q<<<8192, 256, 0, stream>>>(q_f, qq, scal);
  k_quant_kv<<<4096, 256, 0, stream>>>(kv_f, kq, vqt, scal);
  k_attn1<<<dim3(64, 64), 256, 0, stream>>>(qq, kq, rowstats, pstat);
  k_pminmax<<<1, 256, 0, stream>>>(pstat, scal);
  k_attn2<<<dim3(64, 64), 256, 0, stream>>>(qq, kq, vqt, scal, rowstats, attn_o);
  // proj GEMM: 32768x256x256, 128-tile
  k_gemm128<false><<<dim3(2, 256), 256, 0, stream>>>(attn_o, proj_wq, proj_b, out, 32768, 256, nullptr);
}

// Round 12
// 298.589 us; speedup vs baseline: 1.0513x; 1.0460x over previous
//
#include <hip/hip_runtime.h>
#include <stdint.h>

typedef float f32x4 __attribute__((ext_vector_type(4)));
typedef __bf16 bf16x8 __attribute__((ext_vector_type(8)));

#define DEV __device__ __forceinline__

DEV unsigned short f2bf(float f) {
  unsigned u = __float_as_uint(f);
  u += 0x7FFFu + ((u >> 16) & 1u);   // round-to-nearest-even
  return (unsigned short)(u >> 16);
}

DEV float exp2_(float x) {
#if __has_builtin(__builtin_amdgcn_exp2f)
  return __builtin_amdgcn_exp2f(x);   // raw v_exp_f32; args in [-60,0] => normal range
#else
  return exp2f(x);
#endif
}

// scal: [0..3]=wmax(q,kv,sr,proj), [4]=qmax, [5]=kmax, [6]=vmax, [7]=pmin, [8]=pmax
__global__ void k_init(float* scal) {
  int t = threadIdx.x;
  if (t < 16) scal[t] = (t == 7) ? __uint_as_float(0x7f800000u) : 0.f;
}

__global__ __launch_bounds__(256) void k_absmax4(const float* w0, const float* w1,
                                                 const float* w2, const float* w3, float* scal) {
  const float* srcs[4] = {w0, w1, w2, w3};
  const int ns[4] = {65536, 131072, 1048576, 65536};
  int t = blockIdx.y;
  const float* src = srcs[t];
  int n = ns[t];
  float m = 0.f;
  for (int i = blockIdx.x * 256 + threadIdx.x; i < n; i += gridDim.x * 256)
    m = fmaxf(m, fabsf(src[i]));
  #pragma unroll
  for (int d = 1; d < 64; d <<= 1) m = fmaxf(m, __shfl_xor(m, d, 64));
  __shared__ float red[4];
  if ((threadIdx.x & 63) == 0) red[threadIdx.x >> 6] = m;
  __syncthreads();
  if (threadIdx.x == 0) {
    m = fmaxf(fmaxf(red[0], red[1]), fmaxf(red[2], red[3]));
    atomicMax((unsigned*)(scal + t), __float_as_uint(m));
  }
}

// batched weight quant: y=0 -> q_w(65536, slot0), y=1 -> kv_w(131072, slot1), y=2 -> proj_w(65536, slot3)
__global__ __launch_bounds__(256) void k_quantw3(const float* w0, const float* w1, const float* w2,
                                                 unsigned short* o0, unsigned short* o1,
                                                 unsigned short* o2, const float* scal) {
  const float* w[3] = {w0, w1, w2};
  unsigned short* o[3] = {o0, o1, o2};
  const int ns[3] = {65536, 131072, 65536};
  const int slots[3] = {0, 1, 3};
  int t = blockIdx.y;
  int i = blockIdx.x * 256 + threadIdx.x;
  if (i >= ns[t]) return;
  float delta = scal[slots[t]] / 127.f + 1e-8f;
  float q = fminf(fmaxf(rintf(w[t][i] / delta), -128.f), 127.f) * delta;
  o[t][i] = f2bf(q);
}

// sr_w (O=256,I=256,4,4) -> W'[o][khkw*256 + i]  (k-order matches fused im2col)
__global__ __launch_bounds__(256) void k_quantsrw(const float* w, unsigned short* o, const float* scal) {
  int tid = blockIdx.x * 256 + threadIdx.x;
  int oo = tid >> 12;
  int rem = tid & 4095;
  int khkw = rem >> 8;
  int i = rem & 255;
  float delta = scal[2] / 127.f + 1e-8f;
  float x = w[oo * 4096 + i * 16 + khkw];
  float q = fminf(fmaxf(rintf(x / delta), -128.f), 127.f) * delta;
  o[tid] = f2bf(q);
}

// ---- 64x64-tile GEMM, K=256, BK=128 (kv: M=2048,N=512) ----
template<bool CVT>
__global__ __launch_bounds__(256) void k_gemm_bk(const void* __restrict__ Ap,
                                                 const unsigned short* __restrict__ W,
                                                 const float* __restrict__ bias,
                                                 float* __restrict__ C,
                                                 int M, int N, float* max_ptr, int split) {
  __shared__ unsigned short As[64 * 136];
  __shared__ unsigned short Bs[64 * 136];
  const int m0 = blockIdx.y * 64, n0 = blockIdx.x * 64;
  const int tid = threadIdx.x;
  const int wid = tid >> 6, lane = tid & 63;
  const int quad = lane >> 4, lr = lane & 15;
  const int wm = wid >> 1, wn = wid & 1;
  f32x4 acc[2][2] = {};
  for (int kb = 0; kb < 256; kb += 128) {
    __syncthreads();
    #pragma unroll
    for (int i = 0; i < 4; i++) {
      int c = i * 256 + tid;              // 1024 chunks of 8 elems
      int row = c >> 4, cu = (c & 15) * 8;
      if (CVT) {
        const float* Af = (const float*)Ap;
        const float* src = Af + (size_t)(m0 + row) * 256 + kb + cu;
        float4 v0 = *(const float4*)src;
        float4 v1 = *(const float4*)(src + 4);
        ushort4 r0, r1;
        r0.x = f2bf(v0.x); r0.y = f2bf(v0.y); r0.z = f2bf(v0.z); r0.w = f2bf(v0.w);
        r1.x = f2bf(v1.x); r1.y = f2bf(v1.y); r1.z = f2bf(v1.z); r1.w = f2bf(v1.w);
        *(ushort4*)&As[row * 136 + cu] = r0;
        *(ushort4*)&As[row * 136 + cu + 4] = r1;
      } else {
        const unsigned short* Ab = (const unsigned short*)Ap;
        *(uint4*)&As[row * 136 + cu] = *(const uint4*)(Ab + (size_t)(m0 + row) * 256 + kb + cu);
      }
      *(uint4*)&Bs[row * 136 + cu] = *(const uint4*)(W + (size_t)(n0 + row) * 256 + kb + cu);
    }
    __syncthreads();
    #pragma unroll
    for (int kc = 0; kc < 4; kc++) {
      bf16x8 af0 = *(const bf16x8*)&As[(wm * 32 + lr) * 136 + kc * 32 + quad * 8];
      bf16x8 af1 = *(const bf16x8*)&As[(wm * 32 + 16 + lr) * 136 + kc * 32 + quad * 8];
      bf16x8 bf0 = *(const bf16x8*)&Bs[(wn * 32 + lr) * 136 + kc * 32 + quad * 8];
      bf16x8 bf1 = *(const bf16x8*)&Bs[(wn * 32 + 16 + lr) * 136 + kc * 32 + quad * 8];
      acc[0][0] = __builtin_amdgcn_mfma_f32_16x16x32_bf16(af0, bf0, acc[0][0], 0, 0, 0);
      acc[0][1] = __builtin_amdgcn_mfma_f32_16x16x32_bf16(af0, bf1, acc[0][1], 0, 0, 0);
      acc[1][0] = __builtin_amdgcn_mfma_f32_16x16x32_bf16(af1, bf0, acc[1][0], 0, 0, 0);
      acc[1][1] = __builtin_amdgcn_mfma_f32_16x16x32_bf16(af1, bf1, acc[1][1], 0, 0, 0);
    }
  }
  float amax = 0.f;
  #pragma unroll
  for (int mi = 0; mi < 2; mi++)
    #pragma unroll
    for (int ni = 0; ni < 2; ni++) {
      int col = n0 + wn * 32 + ni * 16 + lr;
      float bv = bias[col];
      #pragma unroll
      for (int r = 0; r < 4; r++) {
        int row = m0 + wm * 32 + mi * 16 + quad * 4 + r;
        float v = acc[mi][ni][r] + bv;
        C[(size_t)row * N + col] = v;
        amax = fmaxf(amax, fabsf(v));
      }
    }
  if (max_ptr) {
    #pragma unroll
    for (int d = 1; d < 64; d <<= 1) amax = fmaxf(amax, __shfl_xor(amax, d, 64));
    if (lane == 0) {
      int slot = (split > 0 && n0 >= split) ? 1 : 0;
      atomicMax((unsigned*)(max_ptr + slot), __float_as_uint(amax));
    }
  }
}

// ---- 128x128-tile GEMM, K=256, BK=64; 4 waves, 2x2 layout, 64x64 patch/wave ----
template<bool CVT>
__global__ __launch_bounds__(256) void k_gemm128(const void* __restrict__ Ap,
                                                 const unsigned short* __restrict__ W,
                                                 const float* __restrict__ bias,
                                                 float* __restrict__ C,
                                                 int M, int N, float* max_ptr) {
  __shared__ unsigned short As[128 * 72];  // +8 pad: 2-way-max banking
  __shared__ unsigned short Bs[128 * 72];
  const int m0 = blockIdx.y * 128, n0 = blockIdx.x * 128;
  const int tid = threadIdx.x;
  const int wid = tid >> 6, lane = tid & 63;   // 4 waves
  const int quad = lane >> 4, lr = lane & 15;
  const int wm = wid >> 1, wn = wid & 1;       // 2x2 wave grid, 64x64 patch each
  f32x4 acc[4][4] = {};
  for (int kb = 0; kb < 256; kb += 64) {
    __syncthreads();
    #pragma unroll
    for (int i = 0; i < 4; i++) {
      int c = i * 256 + tid;             // 1024 chunks of 8 shorts
      int row = c >> 3, cu = (c & 7) * 8;
      if (CVT) {
        const float* Af = (const float*)Ap;
        const float* src = Af + (size_t)(m0 + row) * 256 + kb + cu;
        float4 v0 = *(const float4*)src;
        float4 v1 = *(const float4*)(src + 4);
        ushort4 r0, r1;
        r0.x = f2bf(v0.x); r0.y = f2bf(v0.y); r0.z = f2bf(v0.z); r0.w = f2bf(v0.w);
        r1.x = f2bf(v1.x); r1.y = f2bf(v1.y); r1.z = f2bf(v1.z); r1.w = f2bf(v1.w);
        *(ushort4*)&As[row * 72 + cu] = r0;
        *(ushort4*)&As[row * 72 + cu + 4] = r1;
      } else {
        const unsigned short* Ab = (const unsigned short*)Ap;
        *(uint4*)&As[row * 72 + cu] = *(const uint4*)(Ab + (size_t)(m0 + row) * 256 + kb + cu);
      }
      *(uint4*)&Bs[row * 72 + cu] = *(const uint4*)(W + (size_t)(n0 + row) * 256 + kb + cu);
    }
    __syncthreads();
    #pragma unroll
    for (int kc = 0; kc < 2; kc++) {
      bf16x8 af[4], bf[4];
      #pragma unroll
      for (int mi = 0; mi < 4; mi++)
        af[mi] = *(const bf16x8*)&As[(wm * 64 + mi * 16 + lr) * 72 + kc * 32 + quad * 8];
      #pragma unroll
      for (int ni = 0; ni < 4; ni++)
        bf[ni] = *(const bf16x8*)&Bs[(wn * 64 + ni * 16 + lr) * 72 + kc * 32 + quad * 8];
      #pragma unroll
      for (int mi = 0; mi < 4; mi++)
        #pragma unroll
        for (int ni = 0; ni < 4; ni++)
          acc[mi][ni] = __builtin_amdgcn_mfma_f32_16x16x32_bf16(af[mi], bf[ni], acc[mi][ni], 0, 0, 0);
    }
  }
  float amax = 0.f;
  #pragma unroll
  for (int mi = 0; mi < 4; mi++)
    #pragma unroll
    for (int ni = 0; ni < 4; ni++) {
      int col = n0 + wn * 64 + ni * 16 + lr;
      float bv = bias[col];
      #pragma unroll
      for (int r = 0; r < 4; r++) {
        int row = m0 + wm * 64 + mi * 16 + quad * 4 + r;
        float v = acc[mi][ni][r] + bv;
        C[(size_t)row * N + col] = v;
        amax = fmaxf(amax, fabsf(v));
      }
    }
  if (max_ptr) {
    #pragma unroll
    for (int d = 1; d < 64; d <<= 1) amax = fmaxf(amax, __shfl_xor(amax, d, 64));
    if (lane == 0) atomicMax((unsigned*)max_ptr, __float_as_uint(amax));
  }
}

// ---- conv GEMM: 2048x256xK4096, split-K=4, im2col+f32->bf16 fused into staging ----
__global__ __launch_bounds__(256) void k_conv_sk(const float* __restrict__ x,
                                                 const unsigned short* __restrict__ W,
                                                 float* __restrict__ C) {
  __shared__ unsigned short As[64 * 136];
  __shared__ unsigned short Bs[64 * 136];
  const int m0 = blockIdx.y * 64, n0 = blockIdx.x * 64;
  const int kOff = blockIdx.z * 1024;
  C += (size_t)blockIdx.z * 2048 * 256;
  const int tid = threadIdx.x;
  const int wid = tid >> 6, lane = tid & 63;
  const int quad = lane >> 4, lr = lane & 15;
  const int wm = wid >> 1, wn = wid & 1;
  f32x4 acc[2][2] = {};
  for (int kb = 0; kb < 1024; kb += 128) {
    __syncthreads();
    #pragma unroll
    for (int i = 0; i < 4; i++) {
      int c = i * 256 + tid;
      int row = c >> 4, cu = (c & 15) * 8;
      int kk = kOff + kb + cu;
      int m = m0 + row;
      int b = m >> 8, p = m & 255, ph = p >> 4, pw = p & 15;
      int q = kk >> 8, ii = kk & 255;
      int n = (ph * 4 + (q >> 2)) * 64 + pw * 4 + (q & 3);
      const float* src = x + ((size_t)(b * 4096 + n) * 256 + ii);
      float4 v0 = *(const float4*)src;
      float4 v1 = *(const float4*)(src + 4);
      ushort4 r0, r1;
      r0.x = f2bf(v0.x); r0.y = f2bf(v0.y); r0.z = f2bf(v0.z); r0.w = f2bf(v0.w);
      r1.x = f2bf(v1.x); r1.y = f2bf(v1.y); r1.z = f2bf(v1.z); r1.w = f2bf(v1.w);
      *(ushort4*)&As[row * 136 + cu] = r0;
      *(ushort4*)&As[row * 136 + cu + 4] = r1;
      *(uint4*)&Bs[row * 136 + cu] = *(const uint4*)(W + (size_t)(n0 + row) * 4096 + kk);
    }
    __syncthreads();
    #pragma unroll
    for (int kc = 0; kc < 4; kc++) {
      bf16x8 af0 = *(const bf16x8*)&As[(wm * 32 + lr) * 136 + kc * 32 + quad * 8];
      bf16x8 af1 = *(const bf16x8*)&As[(wm * 32 + 16 + lr) * 136 + kc * 32 + quad * 8];
      bf16x8 bf0 = *(const bf16x8*)&Bs[(wn * 32 + lr) * 136 + kc * 32 + quad * 8];
      bf16x8 bf1 = *(const bf16x8*)&Bs[(wn * 32 + 16 + lr) * 136 + kc * 32 + quad * 8];
      acc[0][0] = __builtin_amdgcn_mfma_f32_16x16x32_bf16(af0, bf0, acc[0][0], 0, 0, 0);
      acc[0][1] = __builtin_amdgcn_mfma_f32_16x16x32_bf16(af0, bf1, acc[0][1], 0, 0, 0);
      acc[1][0] = __builtin_amdgcn_mfma_f32_16x16x32_bf16(af1, bf0, acc[1][0], 0, 0, 0);
      acc[1][1] = __builtin_amdgcn_mfma_f32_16x16x32_bf16(af1, bf1, acc[1][1], 0, 0, 0);
    }
  }
  #pragma unroll
  for (int mi = 0; mi < 2; mi++)
    #pragma unroll
    for (int ni = 0; ni < 2; ni++) {
      int col = n0 + wn * 32 + ni * 16 + lr;
      #pragma unroll
      for (int r = 0; r < 4; r++) {
        int row = m0 + wm * 32 + mi * 16 + quad * 4 + r;
        C[(size_t)row * 256 + col] = acc[mi][ni][r];
      }
    }
}

// LayerNorm over C=256; sums 4 split-K conv partials + sr_b first
__global__ __launch_bounds__(256) void k_ln(const float* __restrict__ convp, const float* srb,
                                            const float* g, const float* bb,
                                            unsigned short* __restrict__ xn) {
  int row = blockIdx.x, c = threadIdx.x;
  float v = srb[c];
  #pragma unroll
  for (int s = 0; s < 4; s++) v += convp[s * 524288 + row * 256 + c];
  __shared__ float red[4];
  float s = v;
  #pragma unroll
  for (int d = 1; d < 64; d <<= 1) s += __shfl_xor(s, d, 64);
  if ((c & 63) == 0) red[c >> 6] = s;
  __syncthreads();
  float mu = (red[0] + red[1] + red[2] + red[3]) * (1.f / 256.f);
  __syncthreads();
  float dv = v - mu;
  float s2 = dv * dv;
  #pragma unroll
  for (int d = 1; d < 64; d <<= 1) s2 += __shfl_xor(s2, d, 64);
  if ((c & 63) == 0) red[c >> 6] = s2;
  __syncthreads();
  float var = (red[0] + red[1] + red[2] + red[3]) * (1.f / 256.f);
  float rs = 1.f / sqrtf(var + 1e-5f);
  xn[row * 256 + c] = f2bf(dv * rs * g[c] + bb[c]);
}

// q (32768x256 f32) -> quantize -> qq[b,h,n,j] bf16; 4 elems/thread (j stays in one head)
__global__ __launch_bounds__(256) void k_quant_q(const float* __restrict__ q,
                                                 unsigned short* __restrict__ qq,
                                                 const float* scal) {
  int tid = blockIdx.x * 256 + threadIdx.x;
  int i4 = tid * 4;
  float delta = scal[4] / 127.f + 1e-8f;
  float4 v = *(const float4*)(q + i4);
  int c = i4 & 255, bn = i4 >> 8;
  int b = bn >> 12, n = bn & 4095;
  int h = c >> 5, j = c & 31;   // j multiple of 4, j+3 <= 31
  ushort4 r;
  r.x = f2bf(fminf(fmaxf(rintf(v.x / delta), -128.f), 127.f) * delta);
  r.y = f2bf(fminf(fmaxf(rintf(v.y / delta), -128.f), 127.f) * delta);
  r.z = f2bf(fminf(fmaxf(rintf(v.z / delta), -128.f), 127.f) * delta);
  r.w = f2bf(fminf(fmaxf(rintf(v.w / delta), -128.f), 127.f) * delta);
  *(ushort4*)(qq + (((size_t)(b * 8 + h) * 4096 + n) * 32) + j) = r;
}

// kv (2048x512 f32) -> kq[b,h,n2,j] and vqt[b,h,j,n2] bf16
__global__ __launch_bounds__(256) void k_quant_kv(const float* __restrict__ kv,
                                                  unsigned short* __restrict__ kq,
                                                  unsigned short* __restrict__ vqt,
                                                  const float* scal) {
  int tid = blockIdx.x * 256 + threadIdx.x;
  int d = tid & 511, row = tid >> 9;
  int b = row >> 8, n2 = row & 255;
  int t = d >> 8, hj = d & 255;
  int h = hj >> 5, j = hj & 31;
  float delta = scal[5 + t] / 127.f + 1e-8f;
  float qv = fminf(fmaxf(rintf(kv[tid] / delta), -128.f), 127.f) * delta;
  unsigned short r = f2bf(qv);
  if (t == 0) kq[((b * 8 + h) * 256 + n2) * 32 + j] = r;
  else        vqt[((b * 8 + h) * 32 + j) * 256 + n2] = r;
}

// attention pass 1 (exp2 domain): per-row (m2, inv_l) -> rowstats;
// per-BLOCK (wmin, wmax) -> pstat[4096] (no contended atomics).
__global__ __launch_bounds__(256) void k_attn1(const unsigned short* __restrict__ qq,
                                               const unsigned short* __restrict__ kq,
                                               float2* __restrict__ rowstats,
                                               float2* __restrict__ pstat) {
  __shared__ unsigned short Ks[256 * 40];
  __shared__ float red[8];
  const int bh = blockIdx.y;
  const int row0 = blockIdx.x * 64;
  const int tid = threadIdx.x, wid = tid >> 6, lane = tid & 63, quad = lane >> 4, lr = lane & 15;
  const float c2 = 0.17677669529663687f * 1.4426950408889634f;  // 32^-0.5 * log2(e)
  const unsigned short* kbase = kq + (size_t)bh * 256 * 32;
  #pragma unroll
  for (int k = 0; k < 4; k++) {
    int cc = tid + k * 256;
    int rr = cc >> 2, c8 = (cc & 3) * 8;
    *(uint4*)&Ks[rr * 40 + c8] = *(const uint4*)(kbase + rr * 32 + c8);
  }
  __syncthreads();
  bf16x8 af = *(const bf16x8*)(qq + ((size_t)bh * 4096 + row0 + wid * 16 + lr) * 32 + quad * 8);
  f32x4 acc[16] = {};
  #pragma unroll
  for (int t = 0; t < 16; t++) {
    bf16x8 bfr = *(const bf16x8*)&Ks[(t * 16 + lr) * 40 + quad * 8];
    acc[t] = __builtin_amdgcn_mfma_f32_16x16x32_bf16(af, bfr, acc[t], 0, 0, 0);
  }
  float mx4[4], mn4[4];
  #pragma unroll
  for (int r = 0; r < 4; r++) {
    float mx = -1e30f, mn = 1e30f;
    #pragma unroll
    for (int t = 0; t < 16; t++) {
      float s = acc[t][r] * c2;
      mx = fmaxf(mx, s); mn = fminf(mn, s);
    }
    mx4[r] = mx; mn4[r] = mn;
  }
  #pragma unroll
  for (int d = 1; d < 16; d <<= 1) {
    #pragma unroll
    for (int r = 0; r < 4; r++) {
      mx4[r] = fmaxf(mx4[r], __shfl_xor(mx4[r], d, 64));
      mn4[r] = fminf(mn4[r], __shfl_xor(mn4[r], d, 64));
    }
  }
  float l4[4];
  #pragma unroll
  for (int r = 0; r < 4; r++) {
    float l = 0.f;
    #pragma unroll
    for (int t = 0; t < 16; t++) l += exp2_(acc[t][r] * c2 - mx4[r]);
    l4[r] = l;
  }
  #pragma unroll
  for (int d = 1; d < 16; d <<= 1) {
    #pragma unroll
    for (int r = 0; r < 4; r++) l4[r] += __shfl_xor(l4[r], d, 64);
  }
  float wmin = 1e30f, wmax = 0.f;
  #pragma unroll
  for (int r = 0; r < 4; r++) {
    float inv_l = 1.f / l4[r];
    int row = row0 + wid * 16 + quad * 4 + r;
    if (lr == 0) rowstats[(size_t)bh * 4096 + row] = make_float2(mx4[r], inv_l);
    wmax = fmaxf(wmax, inv_l);
    wmin = fminf(wmin, exp2_(mn4[r] - mx4[r]) * inv_l);
  }
  #pragma unroll
  for (int d = 16; d < 64; d <<= 1) {
    wmax = fmaxf(wmax, __shfl_xor(wmax, d, 64));
    wmin = fminf(wmin, __shfl_xor(wmin, d, 64));
  }
  if (lane == 0) { red[wid] = wmin; red[4 + wid] = wmax; }
  __syncthreads();
  if (tid == 0) {
    float mn = fminf(fminf(red[0], red[1]), fminf(red[2], red[3]));
    float mx = fmaxf(fmaxf(red[4], red[5]), fmaxf(red[6], red[7]));
    pstat[blockIdx.y * 64 + blockIdx.x] = make_float2(mn, mx);
  }
}

// reduce pstat[4096] -> scal[7]=pmin, scal[8]=pmax  (single block)
__global__ __launch_bounds__(256) void k_pminmax(const float2* __restrict__ pstat, float* scal) {
  int t = threadIdx.x;
  float mn = 1e30f, mx = 0.f;
  #pragma unroll
  for (int i = 0; i < 16; i++) {
    float2 v = pstat[t + i * 256];
    mn = fminf(mn, v.x); mx = fmaxf(mx, v.y);
  }
  #pragma unroll
  for (int d = 1; d < 64; d <<= 1) {
    mn = fminf(mn, __shfl_xor(mn, d, 64));
    mx = fmaxf(mx, __shfl_xor(mx, d, 64));
  }
  __shared__ float red[8];
  if ((t & 63) == 0) { red[t >> 6] = mn; red[4 + (t >> 6)] = mx; }
  __syncthreads();
  if (t == 0) {
    scal[7] = fminf(fminf(red[0], red[1]), fminf(red[2], red[3]));
    scal[8] = fmaxf(fmaxf(red[4], red[5]), fmaxf(red[6], red[7]));
  }
}

// attention pass 2 (R9 empirical optimum): reduction-free; no barrier between
// QK-MFMA and Ps-writes (MFMA/VALU wave co-scheduling), separate Ks/Vs/Ps.
__global__ __launch_bounds__(256) void k_attn2(const unsigned short* __restrict__ qq,
                                               const unsigned short* __restrict__ kq,
                                               const unsigned short* __restrict__ vqt,
                                               const float* scal,
                                               const float2* __restrict__ rowstats,
                                               unsigned short* __restrict__ attn_out) {
  __shared__ unsigned short Ks[256 * 40];  // 20.0 KB
  __shared__ unsigned short Vs[32 * 264];  // 16.5 KB  V^T [j][m2]
  __shared__ unsigned short Ps[64 * 264];  // 33.0 KB  quantized probs
  const int bh = blockIdx.y, b = bh >> 3, h = bh & 7;
  const int row0 = blockIdx.x * 64;
  const int tid = threadIdx.x, wid = tid >> 6, lane = tid & 63, quad = lane >> 4, lr = lane & 15;
  const float c2 = 0.17677669529663687f * 1.4426950408889634f;
  const unsigned short* kbase = kq + (size_t)bh * 256 * 32;
  #pragma unroll
  for (int k = 0; k < 4; k++) {
    int cc = tid + k * 256;
    int rr = cc >> 2, c8 = (cc & 3) * 8;
    *(uint4*)&Ks[rr * 40 + c8] = *(const uint4*)(kbase + rr * 32 + c8);
  }
  const unsigned short* vbase = vqt + (size_t)bh * 32 * 256;
  #pragma unroll
  for (int k = 0; k < 4; k++) {
    int cc = tid + k * 256;
    int rr = cc >> 5, c8 = (cc & 31) * 8;
    *(uint4*)&Vs[rr * 264 + c8] = *(const uint4*)(vbase + rr * 256 + c8);
  }
  __syncthreads();
  bf16x8 af = *(const bf16x8*)(qq + ((size_t)bh * 4096 + row0 + wid * 16 + lr) * 32 + quad * 8);
  f32x4 acc[16] = {};
  #pragma unroll
  for (int t = 0; t < 16; t++) {
    bf16x8 bfr = *(const bf16x8*)&Ks[(t * 16 + lr) * 40 + quad * 8];
    acc[t] = __builtin_amdgcn_mfma_f32_16x16x32_bf16(af, bfr, acc[t], 0, 0, 0);
  }
  float pmin = scal[7], pmax = scal[8];
  float delta = (pmax - pmin) / 255.f + 1e-8f;
  float inv_delta = 1.f / delta;
  float zp = rintf(-pmin / delta);
  const int rowb = row0 + wid * 16 + quad * 4;
  #pragma unroll
  for (int r = 0; r < 4; r++) {
    float2 st = rowstats[(size_t)bh * 4096 + rowb + r];
    float m2 = st.x, inv_l = st.y;
    int prow = wid * 16 + quad * 4 + r;
    #pragma unroll
    for (int t = 0; t < 16; t++) {
      float p = exp2_(acc[t][r] * c2 - m2) * inv_l;
      float tq = fminf(fmaxf(rintf(p * inv_delta) + zp, 0.f), 255.f);
      Ps[prow * 264 + t * 16 + lr] = f2bf((tq - zp) * delta);
    }
  }
  __syncthreads();
  f32x4 o0 = {}, o1 = {};
  #pragma unroll
  for (int ks = 0; ks < 8; ks++) {
    bf16x8 pa = *(const bf16x8*)&Ps[(wid * 16 + lr) * 264 + ks * 32 + quad * 8];
    bf16x8 b0 = *(const bf16x8*)&Vs[lr * 264 + ks * 32 + quad * 8];
    bf16x8 b1 = *(const bf16x8*)&Vs[(16 + lr) * 264 + ks * 32 + quad * 8];
    o0 = __builtin_amdgcn_mfma_f32_16x16x32_bf16(pa, b0, o0, 0, 0, 0);
    o1 = __builtin_amdgcn_mfma_f32_16x16x32_bf16(pa, b1, o1, 0, 0, 0);
  }
  #pragma unroll
  for (int r = 0; r < 4; r++) {
    int n = row0 + wid * 16 + quad * 4 + r;
    size_t base = ((size_t)(b * 4096) + n) * 256 + h * 32;
    attn_out[base + lr] = f2bf(o0[r]);
    attn_out[base + 16 + lr] = f2bf(o1[r]);
  }
}

extern "C" void kernel_launch(void* const* d_in, const int* in_sizes, int n_in,
                              void* d_out, int out_size, void* d_ws, size_t ws_size,
                              hipStream_t stream) {
  const float* x      = (const float*)d_in[0];
  const float* q_w    = (const float*)d_in[1];
  const float* q_b    = (const float*)d_in[2];
  const float* kv_w   = (const float*)d_in[3];
  const float* kv_b   = (const float*)d_in[4];
  const float* sr_w   = (const float*)d_in[5];
  const float* sr_b   = (const float*)d_in[6];
  const float* norm_g = (const float*)d_in[7];
  const float* norm_b = (const float*)d_in[8];
  const float* proj_w = (const float*)d_in[9];
  const float* proj_b = (const float*)d_in[10];
  float* out = (float*)d_out;

  char* ws = (char*)d_ws;
  float* scal = (float*)ws;
  unsigned short* q_wq    = (unsigned short*)(ws + 256);       // 128 KB
  unsigned short* kv_wq   = (unsigned short*)(ws + 131328);    // 256 KB
  unsigned short* proj_wq = (unsigned short*)(ws + 393472);    // 128 KB
  unsigned short* sr_wq   = (unsigned short*)(ws + 524544);    // 2 MB   -> 2621696
  unsigned short* xn      = (unsigned short*)(ws + 2621696);   // 1 MB   -> 3670272
  float*          kv_f    = (float*)(ws + 3670272);            // 4 MB   -> 7864576
  unsigned short* kq      = (unsigned short*)(ws + 7864576);   // 1 MB   -> 8913152
  unsigned short* vqt     = (unsigned short*)(ws + 8913152);   // 1 MB   -> 9961728
  float2*         rowstats= (float2*)(ws + 9961728);           // 2 MB   -> 12058880
  float*          convp   = (float*)(ws + 12058880);           // 8 MB (4 partials) -> 20447488
  // aliases (stream-ordered lifetimes):
  float*          q_f     = (float*)(ws + 12058880);           // over convp (dead after k_ln); 32 MB -> 45613312
  unsigned short* qq      = (unsigned short*)(ws + 45613312);  // 16 MB -> 62390528
  unsigned short* attn_o  = (unsigned short*)(ws + 12058880);  // over q_f (dead after k_quant_q); 16 MB -> 28836096
  float2*         pstat   = (float2*)(ws + 28836096);          // 32 KB, in dead upper q_f region

  k_init<<<1, 64, 0, stream>>>(scal);
  k_absmax4<<<dim3(64, 4), 256, 0, stream>>>(q_w, kv_w, sr_w, proj_w, scal);
  k_quantw3<<<dim3(512, 3), 256, 0, stream>>>(q_w, kv_w, proj_w, q_wq, kv_wq, proj_wq, scal);
  k_quantsrw<<<4096, 256, 0, stream>>>(sr_w, sr_wq, scal);
  // conv GEMM (im2col+cast fused, split-K=4): 2048x256x4096
  k_conv_sk<<<dim3(4, 32, 4), 256, 0, stream>>>(x, sr_wq, convp);
  k_ln<<<2048, 256, 0, stream>>>(convp, sr_b, norm_g, norm_b, xn);
  // kv GEMM: 2048x512x256
  k_gemm_bk<false><<<dim3(8, 32), 256, 0, stream>>>(xn, kv_wq, kv_b, kv_f, 2048, 512, scal + 5, 256);
  // q GEMM: 32768x256x256, 128-tile (reads x f32, converts in staging)
  k_gemm128<true><<<dim3(2, 256), 256, 0, stream>>>(x, q_wq, q_b, q_f, 32768, 256, scal + 4);
  k_quant_q<<<8192, 256, 0, stream>>>(q_f, qq, scal);
  k_quant_kv<<<4096, 256, 0, stream>>>(kv_f, kq, vqt, scal);
  k_attn1<<<dim3(64, 64), 256, 0, stream>>>(qq, kq, rowstats, pstat);
  k_pminmax<<<1, 256, 0, stream>>>(pstat, scal);
  k_attn2<<<dim3(64, 64), 256, 0, stream>>>(qq, kq, vqt, scal, rowstats, attn_o);
  // proj GEMM: 32768x256x256, 128-tile
  k_gemm128<false><<<dim3(2, 256), 256, 0, stream>>>(attn_o, proj_wq, proj_b, out, 32768, 256, nullptr);
}